// Round 14
// baseline (73.923 us; speedup 1.0000x reference)
//
#include <hip/hip_runtime.h>
#include <hip/hip_bf16.h>
#include <math.h>

#define S_LEN 4096

typedef unsigned short u16t;
typedef unsigned int u32t;
typedef __attribute__((ext_vector_type(4))) short bf16x4;
typedef __attribute__((ext_vector_type(8))) short bf16x8;
typedef __attribute__((ext_vector_type(4))) float f32x4;

__device__ __forceinline__ u16t f2bf_u16(float f) {
  union { __hip_bfloat16 h; u16t u; } r; r.h = __float2bfloat16(f); return r.u;
}

// async global->LDS, 16B per lane; LDS dest = wave-uniform base + lane*16
__device__ __forceinline__ void stage16(const u16t* g, u16t* l) {
  __builtin_amdgcn_global_load_lds(
      (const __attribute__((address_space(1))) void*)g,
      (__attribute__((address_space(3))) void*)l, 16, 0, 0);
}

// ---------------- fused prep: tcast | castw(wq) | castw(wo) | rope ----------------
__global__ __launch_bounds__(256) void prep_kernel(
    const float* __restrict__ x, u16t* __restrict__ xT,
    const float* __restrict__ qkvw, u16t* __restrict__ wq,
    const float* __restrict__ outw, u16t* __restrict__ wo,
    const int* __restrict__ pos, float* __restrict__ cosT, float* __restrict__ sinT)
{
  __shared__ float T[64][65];
  const int b = blockIdx.x;
  const int t = threadIdx.x;
  if (b < 768) {
    int s0 = (b & 63) * 64, c0 = (b >> 6) * 64;
    int sl = t & 63, g = t >> 6;
#pragma unroll
    for (int r = 0; r < 16; ++r) {
      int cl = g + 4 * r;
      T[cl][sl] = x[(size_t)(c0 + cl) * S_LEN + s0 + sl];
    }
    __syncthreads();
#pragma unroll
    for (int r = 0; r < 16; ++r) {
      int sl2 = g + 4 * r;
      xT[(size_t)(s0 + sl2) * 768 + c0 + sl] = f2bf_u16(T[sl][sl2]);
    }
  } else if (b < 3072) {
    const float* src; u16t* dst; int i;
    if (b < 2496) { src = qkvw; dst = wq; i = (b - 768) * 256 + t; }
    else          { src = outw; dst = wo; i = (b - 2496) * 256 + t; }
    float4 v = ((const float4*)src)[i];
    union { u16t h[4]; uint2 u; } r;
    r.h[0] = f2bf_u16(v.x); r.h[1] = f2bf_u16(v.y);
    r.h[2] = f2bf_u16(v.z); r.h[3] = f2bf_u16(v.w);
    ((uint2*)dst)[i] = r.u;
  } else {
    // float trig: worst-case angle err ~4e-4 rad << bf16 quantization of q/k
    int idx = (b - 3072) * 256 + t;
    int j = idx >> 12, s = idx & 4095;
    float p = (float)pos[s];
    float inv = exp2f(-((float)(2 * j) / 64.0f) * 13.2877123795549f); // log2(1e4)
    float a = p * inv;
    cosT[idx] = cosf(a);
    sinT[idx] = sinf(a);
  }
}

// ---------------- bf16 MFMA GEMM, 128x128 tile, BK=32, dual-tile phases ----
// (frozen from round 12; see comments there. sched_barrier(0) pins REQUIRED.)
template <int MODE>
__global__ __launch_bounds__(256, 3) void gemm_kernel(
    const u16t* __restrict__ A, const u16t* __restrict__ Bt,
    void* __restrict__ C1, void* __restrict__ C2,
    const float* __restrict__ cosT, const float* __restrict__ sinT, int ropeRows,
    int tilesX, int rectW, int rectH)
{
  __shared__ __align__(16) u16t smem[24576];   // 3 x 16KB buffers; epilogue reuses
  const int t = threadIdx.x;
  const int lane = t & 63, w = t >> 6;
  const int wr = w >> 1, wc = w & 1;
  const int ln15 = lane & 15, ln4 = lane >> 4;

  const int xcd = blockIdx.x & 7;
  const int local = blockIdx.x >> 3;
  const int nrectX = tilesX / rectW;
  const int lm = local / rectW, ln = local - lm * rectW;
  const int m0 = ((xcd / nrectX) * rectH + lm) * 128;
  const int n0 = ((xcd % nrectX) * rectW + ln) * 128;

  f32x4 acc[4][4];
#pragma unroll
  for (int i = 0; i < 4; ++i)
#pragma unroll
    for (int j = 0; j < 4; ++j) acc[i][j] = (f32x4){0.f, 0.f, 0.f, 0.f};

  const int srow = w * 32 + (lane >> 2);
  const int sch  = ((lane & 3) ^ ((lane >> 3) & 3)) * 8;
  const u16t* gA0 = A  + (size_t)(m0 + srow) * 768 + sch;
  const u16t* gB0 = Bt + (size_t)(n0 + srow) * 768 + sch;
  const u16t* gA1 = gA0 + 16 * 768;
  const u16t* gB1 = gB0 + 16 * 768;
  const int dA = w * 1024;
  const int dB = 4096 + w * 1024;

#pragma unroll
  for (int p = 0; p < 3; ++p) {
    u16t* b = smem + p * 8192;
    stage16(gA0 + p * 32, b + dA);
    stage16(gA1 + p * 32, b + dA + 512);
    stage16(gB0 + p * 32, b + dB);
    stage16(gB1 + p * 32, b + dB + 512);
  }

  const int sg = (ln4 ^ ((ln15 >> 1) & 3)) * 8;

#pragma unroll
  for (int ph = 0; ph < 12; ++ph) {
    const int b0 = (2 * ph) % 3;
    const int b1 = (2 * ph + 1) % 3;
    u16t* c0 = smem + b0 * 8192;
    u16t* c1 = smem + b1 * 8192;
    if (ph < 11) asm volatile("s_waitcnt vmcnt(4)" ::: "memory");
    else         asm volatile("s_waitcnt vmcnt(0)" ::: "memory");
    __builtin_amdgcn_s_barrier();
    __builtin_amdgcn_sched_barrier(0);   // ds_reads must not hoist above barrier
    {
      bf16x8 af[4], bg[4];
#pragma unroll
      for (int f = 0; f < 4; ++f) {
        af[f] = *(const bf16x8*)(c0 + (wr * 64 + f * 16 + ln15) * 32 + sg);
        bg[f] = *(const bf16x8*)(c0 + 4096 + (wc * 64 + f * 16 + ln15) * 32 + sg);
      }
#pragma unroll
      for (int i = 0; i < 4; ++i)
#pragma unroll
        for (int j = 0; j < 4; ++j)
          acc[i][j] = __builtin_amdgcn_mfma_f32_16x16x32_bf16(af[i], bg[j], acc[i][j], 0, 0, 0);
#pragma unroll
      for (int f = 0; f < 4; ++f) {
        af[f] = *(const bf16x8*)(c1 + (wr * 64 + f * 16 + ln15) * 32 + sg);
        bg[f] = *(const bf16x8*)(c1 + 4096 + (wc * 64 + f * 16 + ln15) * 32 + sg);
      }
#pragma unroll
      for (int i = 0; i < 4; ++i)
#pragma unroll
        for (int j = 0; j < 4; ++j)
          acc[i][j] = __builtin_amdgcn_mfma_f32_16x16x32_bf16(af[i], bg[j], acc[i][j], 0, 0, 0);
    }
    __builtin_amdgcn_sched_barrier(0);   // reads complete before the barrier
    __builtin_amdgcn_s_barrier();        // all waves done reading c0/c1
    __builtin_amdgcn_sched_barrier(0);   // refill must not hoist above barrier
    if (ph <= 9) {
      const int ko3 = (2 * ph + 3) * 32;   // -> buf b0
      const int ko4 = (2 * ph + 4) * 32;   // -> buf b1
      stage16(gA0 + ko3, c0 + dA);
      stage16(gA1 + ko3, c0 + dA + 512);
      stage16(gB0 + ko3, c0 + dB);
      stage16(gB1 + ko3, c0 + dB + 512);
      stage16(gA0 + ko4, c1 + dA);
      stage16(gA1 + ko4, c1 + dA + 512);
      stage16(gB0 + ko4, c1 + dB);
      stage16(gB1 + ko4, c1 + dB + 512);
    } else if (ph == 10) {
      const int ko3 = 23 * 32;             // tile 23 -> buf b0 (23%3 == b0)
      stage16(gA0 + ko3, c0 + dA);
      stage16(gA1 + ko3, c0 + dA + 512);
      stage16(gB0 + ko3, c0 + dB);
      stage16(gB1 + ko3, c0 + dB + 512);
    }
  }

  const int mq = m0 + wr * 64;
  if (mq < ropeRows) {
#pragma unroll
    for (int j4 = 0; j4 < 4; ++j4)
#pragma unroll
      for (int nf = 0; nf < 4; ++nf) {
        int n = n0 + wc * 64 + nf * 16 + ln15;
#pragma unroll
        for (int p = 0; p < 2; ++p) {
          int fidx = p * 16 + ln4 * 4 + j4;
          float cc = cosT[fidx * S_LEN + n], ss = sinT[fidx * S_LEN + n];
          float lo = acc[p][nf][j4], hi = acc[p + 2][nf][j4];
          acc[p][nf][j4]     = lo * cc - hi * ss;
          acc[p + 2][nf][j4] = hi * cc + lo * ss;
        }
      }
  }

  if (MODE == 1 && m0 < 1536) {
    __syncthreads();
    u16t* Cs = smem;
#pragma unroll
    for (int i = 0; i < 4; ++i)
#pragma unroll
      for (int nf = 0; nf < 4; ++nf) {
        int n_l = wc * 64 + nf * 16 + ln15;
        int m_l = wr * 64 + i * 16 + ln4 * 4;
        union { u16t h[4]; uint2 u2; } pk;
#pragma unroll
        for (int j4 = 0; j4 < 4; ++j4) pk.h[j4] = f2bf_u16(acc[i][nf][j4]);
        *(uint2*)(Cs + n_l * 136 + m_l) = pk.u2;
      }
    __syncthreads();
    u16t* Co = (u16t*)C1;   // qkT [4096][1536]
#pragma unroll
    for (int it = 0; it < 8; ++it) {
      int idx = it * 256 + t;
      int row = idx >> 4, ch = idx & 15;
      *(uint4*)&Co[(size_t)(n0 + row) * 1536 + m0 + ch * 8] =
          *(const uint4*)&Cs[row * 136 + ch * 8];
    }
  } else if (MODE == 1) {
    __syncthreads();
    u16t* Cs = smem;
#pragma unroll
    for (int i = 0; i < 4; ++i)
#pragma unroll
      for (int j4 = 0; j4 < 4; ++j4) {
        int mrow = wr * 64 + i * 16 + ln4 * 4 + j4;
#pragma unroll
        for (int nf = 0; nf < 4; ++nf) {
          int col = wc * 64 + nf * 16 + ln15;
          Cs[mrow * 128 + col] = f2bf_u16(acc[i][nf][j4]);
        }
      }
    __syncthreads();
    u16t* Co = (u16t*)C2;
#pragma unroll
    for (int it = 0; it < 8; ++it) {
      int idx = it * 256 + t;
      int row = idx >> 4, ch = idx & 15;
      *(uint4*)&Co[(size_t)(m0 - 1536 + row) * S_LEN + n0 + ch * 8] =
          *(const uint4*)&Cs[row * 128 + ch * 8];
    }
  } else {
    float* Co = (float*)C1;
#pragma unroll
    for (int i = 0; i < 4; ++i)
#pragma unroll
      for (int j4 = 0; j4 < 4; ++j4) {
        int m = m0 + wr * 64 + i * 16 + ln4 * 4 + j4;
#pragma unroll
        for (int nf = 0; nf < 4; ++nf)
          Co[(size_t)m * S_LEN + n0 + wc * 64 + nf * 16 + ln15] = acc[i][nf][j4];
      }
  }
}

// ---------------- windowed attention via MFMA, zero-staging / zero-barrier ----
// K/V fragments are contiguous 16B in global (qkT token-major / vbuf natural)
// and L2-resident (~1MB/head, XCD-chunked blocks share panels) -> read direct,
// no LDS staging (guide m169: staging L2-fit data is pure overhead). LDS holds
// only P (per-wave-private rows) -> NO __syncthreads in the whole kernel.
// OOB: K row index clamped (finite data; scores masked by inw), V chunks
// zero-selected (prevents 0 x NaN in PV).
__global__ __launch_bounds__(256, 3) void attn_kernel(
    const u16t* __restrict__ qkT, const u16t* __restrict__ vbuf,
    const float* __restrict__ amask, u16t* __restrict__ attnT)
{
  __shared__ __align__(16) u16t Pl[64 * 192];   // 24576 B, rows private per wave

  const int t = threadIdx.x;
  const int lane = t & 63, w = t >> 6;
  const int fr = lane & 15, fc = lane >> 4;

  const int nid = (blockIdx.x & 7) * 96 + (blockIdx.x >> 3);
  const int h = nid / 64, qt = nid % 64;
  const int q0 = qt * 64;
  const int kstart = q0 - 64;

  // Q fragments direct global->reg (rows q0 + w*16 + fr)
  const u16t* qrow = qkT + (size_t)(q0 + w * 16 + fr) * 1536 + h * 64;
  bf16x8 qa0 = *(const bf16x8*)(qrow + fc * 8);
  bf16x8 qa1 = *(const bf16x8*)(qrow + 32 + fc * 8);

  // amask: predicated issue-early loads (only in-window lanes fetch)
  float am[12][4];
  const int qb = q0 + w * 16 + fc * 4;
#pragma unroll
  for (int nt = 0; nt < 12; ++nt) {
    int kk = nt * 16 + fr;
    int key = kstart + kk;
#pragma unroll
    for (int r = 0; r < 4; ++r) {
      int q = w * 16 + fc * 4 + r;
      int dk = kk - q;
      bool inw = (key >= 0) && (key < S_LEN) && (dk >= 0) && (dk <= 128);
      am[nt][r] = inw ? amask[(size_t)(qb + r) * S_LEN + key] : 0.f;
    }
  }

  // QK^T: direct-global K fragments (16B contiguous in qkT rows)
  const u16t* kbase = qkT + 768 + h * 64;
  f32x4 acc[12];
#pragma unroll
  for (int nt = 0; nt < 12; ++nt) acc[nt] = (f32x4){0.f, 0.f, 0.f, 0.f};
  __builtin_amdgcn_s_setprio(1);
#pragma unroll
  for (int nt = 0; nt < 12; ++nt) {
    int row = nt * 16 + fr;
    int keyc = min(max(kstart + row, 0), S_LEN - 1);   // clamp: finite data, masked below
    const u16t* kr = kbase + (size_t)keyc * 1536;
    bf16x8 kb0 = *(const bf16x8*)(kr + fc * 8);
    acc[nt] = __builtin_amdgcn_mfma_f32_16x16x32_bf16(qa0, kb0, acc[nt], 0, 0, 0);
    bf16x8 kb1 = *(const bf16x8*)(kr + 32 + fc * 8);
    acc[nt] = __builtin_amdgcn_mfma_f32_16x16x32_bf16(qa1, kb1, acc[nt], 0, 0, 0);
  }
  __builtin_amdgcn_s_setprio(0);

  float rm[4] = {-3.0e38f, -3.0e38f, -3.0e38f, -3.0e38f};
#pragma unroll
  for (int nt = 0; nt < 12; ++nt) {
    int kk = nt * 16 + fr;
    int key = kstart + kk;
#pragma unroll
    for (int r = 0; r < 4; ++r) {
      int q = w * 16 + fc * 4 + r;
      int dk = kk - q;
      bool inw = (key >= 0) && (key < S_LEN) && (dk >= 0) && (dk <= 128);
      float s = -3.0e38f;
      if (inw) s = acc[nt][r] * 0.125f + am[nt][r];
      acc[nt][r] = s;
      rm[r] = fmaxf(rm[r], s);
    }
  }
#pragma unroll
  for (int r = 0; r < 4; ++r)
#pragma unroll
    for (int off = 1; off < 16; off <<= 1)
      rm[r] = fmaxf(rm[r], __shfl_xor(rm[r], off));

  float rs[4] = {0.f, 0.f, 0.f, 0.f};
#pragma unroll
  for (int nt = 0; nt < 12; ++nt)
#pragma unroll
    for (int r = 0; r < 4; ++r) {
      float e = __expf(acc[nt][r] - rm[r]);
      acc[nt][r] = e;
      rs[r] += e;
    }
#pragma unroll
  for (int r = 0; r < 4; ++r)
#pragma unroll
    for (int off = 1; off < 16; off <<= 1)
      rs[r] += __shfl_xor(rs[r], off);

  // P -> LDS (chunk-swizzled); NO barrier: rows [w*16,w*16+16) are wave-private,
  // within-wave ds_write->ds_read RAW is lgkm-ordered by the compiler.
#pragma unroll
  for (int nt = 0; nt < 12; ++nt) {
    int kk = nt * 16 + fr;
    int cg = kk >> 3;
#pragma unroll
    for (int r = 0; r < 4; ++r) {
      int q = w * 16 + fc * 4 + r;
      int csw = (cg & 24) | ((cg & 7) ^ (q & 7));
      Pl[q * 192 + csw * 8 + (kk & 7)] = f2bf_u16(acc[nt][r]);
    }
  }

  // PV: pa from swizzled LDS chunk csA (= global chunk cg), vb direct-global
  // chunk cg (16B contiguous in vbuf row d), zero-selected when OOB.
  f32x4 acc2[4];
#pragma unroll
  for (int nt = 0; nt < 4; ++nt) acc2[nt] = (f32x4){0.f, 0.f, 0.f, 0.f};
  __builtin_amdgcn_s_setprio(1);
#pragma unroll
  for (int c32 = 0; c32 < 6; ++c32) {
    int cg = c32 * 4 + fc;
    int csA = (cg & 24) | ((cg & 7) ^ (fr & 7));
    bf16x8 pa = *(const bf16x8*)(Pl + (w * 16 + fr) * 192 + csA * 8);
    int k8 = kstart + cg * 8;
    bool ok = (k8 >= 0) && (k8 < S_LEN);
#pragma unroll
    for (int nt = 0; nt < 4; ++nt) {
      int d = nt * 16 + fr;
      bf16x8 vb = ok ? *(const bf16x8*)(vbuf + (size_t)(h * 64 + d) * S_LEN + k8)
                     : (bf16x8){0, 0, 0, 0, 0, 0, 0, 0};
      acc2[nt] = __builtin_amdgcn_mfma_f32_16x16x32_bf16(pa, vb, acc2[nt], 0, 0, 0);
    }
  }
  __builtin_amdgcn_s_setprio(0);

  float inv[4];
#pragma unroll
  for (int r = 0; r < 4; ++r) inv[r] = 1.f / rs[r];
#pragma unroll
  for (int nt = 0; nt < 4; ++nt)
#pragma unroll
    for (int r = 0; r < 4; ++r) {
      int q = w * 16 + fc * 4 + r;
      int d = nt * 16 + fr;
      attnT[(size_t)(q0 + q) * 768 + h * 64 + d] = f2bf_u16(acc2[nt][r] * inv[r]);
    }
}

extern "C" void kernel_launch(void* const* d_in, const int* in_sizes, int n_in,
                              void* d_out, int out_size, void* d_ws, size_t ws_size,
                              hipStream_t stream) {
  const float* x     = (const float*)d_in[0];
  const int*   pos   = (const int*)d_in[1];
  const float* amask = (const float*)d_in[2];
  const float* qkvw  = (const float*)d_in[3];
  const float* outw  = (const float*)d_in[4];
  float* out = (float*)d_out;

  char* ws = (char*)d_ws;
  float* cosT   = (float*)ws;                          ws += 32 * S_LEN * 4;
  float* sinT   = (float*)ws;                          ws += 32 * S_LEN * 4;
  u16t*  xT     = (u16t*)ws;                           ws += (size_t)S_LEN * 768 * 2;
  u16t*  wq_bf  = (u16t*)ws;                           ws += (size_t)2304 * 768 * 2;
  u16t*  wo_bf  = (u16t*)ws;                           ws += (size_t)768 * 768 * 2;
  u16t*  qkT    = (u16t*)ws;                           ws += (size_t)S_LEN * 1536 * 2;
  u16t*  vbuf   = (u16t*)ws;                           ws += (size_t)768 * S_LEN * 2;
  u16t*  attnT  = (u16t*)ws;

  // fused prep: tcast(768) | castw wq(1728) | castw wo(576) | rope(512)
  prep_kernel<<<3584, 256, 0, stream>>>(x, xT, qkvw, wq_bf, outw, wo_bf, pos, cosT, sinT);
  // QKV: 18x32 tiles, XCD rect = 9m x 8n
  gemm_kernel<1><<<576, 256, 0, stream>>>(wq_bf, xT, qkT, vbuf, cosT, sinT, 1536, 32, 8, 9);
  attn_kernel<<<768, 256, 0, stream>>>(qkT, vbuf, amask, attnT);
  // out-proj: 6x32 tiles, XCD rect = 6m x 4n
  gemm_kernel<0><<<192, 256, 0, stream>>>(wo_bf, attnT, out, nullptr, cosT, sinT, 0, 32, 4, 6);
}

// Round 15
// 62.678 us; speedup vs baseline: 1.1794x; 1.1794x over previous
//
#include <hip/hip_runtime.h>
#include <hip/hip_bf16.h>
#include <math.h>

#define S_LEN 4096

typedef unsigned short u16t;
typedef unsigned int u32t;
typedef __attribute__((ext_vector_type(4))) short bf16x4;
typedef __attribute__((ext_vector_type(8))) short bf16x8;
typedef __attribute__((ext_vector_type(4))) float f32x4;

__device__ __forceinline__ u16t f2bf_u16(float f) {
  union { __hip_bfloat16 h; u16t u; } r; r.h = __float2bfloat16(f); return r.u;
}

// async global->LDS, 16B per lane; LDS dest = wave-uniform base + lane*16
__device__ __forceinline__ void stage16(const u16t* g, u16t* l) {
  __builtin_amdgcn_global_load_lds(
      (const __attribute__((address_space(1))) void*)g,
      (__attribute__((address_space(3))) void*)l, 16, 0, 0);
}

// ---------------- fused prep: tcast | castw(wq) | castw(wo) | rope ----------------
__global__ __launch_bounds__(256) void prep_kernel(
    const float* __restrict__ x, u16t* __restrict__ xT,
    const float* __restrict__ qkvw, u16t* __restrict__ wq,
    const float* __restrict__ outw, u16t* __restrict__ wo,
    const int* __restrict__ pos, float* __restrict__ cosT, float* __restrict__ sinT)
{
  __shared__ float T[64][65];
  const int b = blockIdx.x;
  const int t = threadIdx.x;
  if (b < 768) {
    int s0 = (b & 63) * 64, c0 = (b >> 6) * 64;
    int sl = t & 63, g = t >> 6;
#pragma unroll
    for (int r = 0; r < 16; ++r) {
      int cl = g + 4 * r;
      T[cl][sl] = x[(size_t)(c0 + cl) * S_LEN + s0 + sl];
    }
    __syncthreads();
#pragma unroll
    for (int r = 0; r < 16; ++r) {
      int sl2 = g + 4 * r;
      xT[(size_t)(s0 + sl2) * 768 + c0 + sl] = f2bf_u16(T[sl][sl2]);
    }
  } else if (b < 3072) {
    const float* src; u16t* dst; int i;
    if (b < 2496) { src = qkvw; dst = wq; i = (b - 768) * 256 + t; }
    else          { src = outw; dst = wo; i = (b - 2496) * 256 + t; }
    float4 v = ((const float4*)src)[i];
    union { u16t h[4]; uint2 u; } r;
    r.h[0] = f2bf_u16(v.x); r.h[1] = f2bf_u16(v.y);
    r.h[2] = f2bf_u16(v.z); r.h[3] = f2bf_u16(v.w);
    ((uint2*)dst)[i] = r.u;
  } else {
    // float trig: worst-case angle err ~4e-4 rad << bf16 quantization of q/k
    int idx = (b - 3072) * 256 + t;
    int j = idx >> 12, s = idx & 4095;
    float p = (float)pos[s];
    float inv = exp2f(-((float)(2 * j) / 64.0f) * 13.2877123795549f); // log2(1e4)
    float a = p * inv;
    cosT[idx] = cosf(a);
    sinT[idx] = sinf(a);
  }
}

// ---------------- bf16 MFMA GEMM, 128x128 tile, BK=32, dual-tile phases ----
// (frozen from round 12; see comments there. sched_barrier(0) pins REQUIRED.)
template <int MODE>
__global__ __launch_bounds__(256, 3) void gemm_kernel(
    const u16t* __restrict__ A, const u16t* __restrict__ Bt,
    void* __restrict__ C1, void* __restrict__ C2,
    const float* __restrict__ cosT, const float* __restrict__ sinT, int ropeRows,
    int tilesX, int rectW, int rectH)
{
  __shared__ __align__(16) u16t smem[24576];   // 3 x 16KB buffers; epilogue reuses
  const int t = threadIdx.x;
  const int lane = t & 63, w = t >> 6;
  const int wr = w >> 1, wc = w & 1;
  const int ln15 = lane & 15, ln4 = lane >> 4;

  const int xcd = blockIdx.x & 7;
  const int local = blockIdx.x >> 3;
  const int nrectX = tilesX / rectW;
  const int lm = local / rectW, ln = local - lm * rectW;
  const int m0 = ((xcd / nrectX) * rectH + lm) * 128;
  const int n0 = ((xcd % nrectX) * rectW + ln) * 128;

  f32x4 acc[4][4];
#pragma unroll
  for (int i = 0; i < 4; ++i)
#pragma unroll
    for (int j = 0; j < 4; ++j) acc[i][j] = (f32x4){0.f, 0.f, 0.f, 0.f};

  const int srow = w * 32 + (lane >> 2);
  const int sch  = ((lane & 3) ^ ((lane >> 3) & 3)) * 8;
  const u16t* gA0 = A  + (size_t)(m0 + srow) * 768 + sch;
  const u16t* gB0 = Bt + (size_t)(n0 + srow) * 768 + sch;
  const u16t* gA1 = gA0 + 16 * 768;
  const u16t* gB1 = gB0 + 16 * 768;
  const int dA = w * 1024;
  const int dB = 4096 + w * 1024;

#pragma unroll
  for (int p = 0; p < 3; ++p) {
    u16t* b = smem + p * 8192;
    stage16(gA0 + p * 32, b + dA);
    stage16(gA1 + p * 32, b + dA + 512);
    stage16(gB0 + p * 32, b + dB);
    stage16(gB1 + p * 32, b + dB + 512);
  }

  const int sg = (ln4 ^ ((ln15 >> 1) & 3)) * 8;

#pragma unroll
  for (int ph = 0; ph < 12; ++ph) {
    const int b0 = (2 * ph) % 3;
    const int b1 = (2 * ph + 1) % 3;
    u16t* c0 = smem + b0 * 8192;
    u16t* c1 = smem + b1 * 8192;
    if (ph < 11) asm volatile("s_waitcnt vmcnt(4)" ::: "memory");
    else         asm volatile("s_waitcnt vmcnt(0)" ::: "memory");
    __builtin_amdgcn_s_barrier();
    __builtin_amdgcn_sched_barrier(0);   // ds_reads must not hoist above barrier
    {
      bf16x8 af[4], bg[4];
#pragma unroll
      for (int f = 0; f < 4; ++f) {
        af[f] = *(const bf16x8*)(c0 + (wr * 64 + f * 16 + ln15) * 32 + sg);
        bg[f] = *(const bf16x8*)(c0 + 4096 + (wc * 64 + f * 16 + ln15) * 32 + sg);
      }
#pragma unroll
      for (int i = 0; i < 4; ++i)
#pragma unroll
        for (int j = 0; j < 4; ++j)
          acc[i][j] = __builtin_amdgcn_mfma_f32_16x16x32_bf16(af[i], bg[j], acc[i][j], 0, 0, 0);
#pragma unroll
      for (int f = 0; f < 4; ++f) {
        af[f] = *(const bf16x8*)(c1 + (wr * 64 + f * 16 + ln15) * 32 + sg);
        bg[f] = *(const bf16x8*)(c1 + 4096 + (wc * 64 + f * 16 + ln15) * 32 + sg);
      }
#pragma unroll
      for (int i = 0; i < 4; ++i)
#pragma unroll
        for (int j = 0; j < 4; ++j)
          acc[i][j] = __builtin_amdgcn_mfma_f32_16x16x32_bf16(af[i], bg[j], acc[i][j], 0, 0, 0);
    }
    __builtin_amdgcn_sched_barrier(0);   // reads complete before the barrier
    __builtin_amdgcn_s_barrier();        // all waves done reading c0/c1
    __builtin_amdgcn_sched_barrier(0);   // refill must not hoist above barrier
    if (ph <= 9) {
      const int ko3 = (2 * ph + 3) * 32;   // -> buf b0
      const int ko4 = (2 * ph + 4) * 32;   // -> buf b1
      stage16(gA0 + ko3, c0 + dA);
      stage16(gA1 + ko3, c0 + dA + 512);
      stage16(gB0 + ko3, c0 + dB);
      stage16(gB1 + ko3, c0 + dB + 512);
      stage16(gA0 + ko4, c1 + dA);
      stage16(gA1 + ko4, c1 + dA + 512);
      stage16(gB0 + ko4, c1 + dB);
      stage16(gB1 + ko4, c1 + dB + 512);
    } else if (ph == 10) {
      const int ko3 = 23 * 32;             // tile 23 -> buf b0 (23%3 == b0)
      stage16(gA0 + ko3, c0 + dA);
      stage16(gA1 + ko3, c0 + dA + 512);
      stage16(gB0 + ko3, c0 + dB);
      stage16(gB1 + ko3, c0 + dB + 512);
    }
  }

  const int mq = m0 + wr * 64;
  if (mq < ropeRows) {
#pragma unroll
    for (int j4 = 0; j4 < 4; ++j4)
#pragma unroll
      for (int nf = 0; nf < 4; ++nf) {
        int n = n0 + wc * 64 + nf * 16 + ln15;
#pragma unroll
        for (int p = 0; p < 2; ++p) {
          int fidx = p * 16 + ln4 * 4 + j4;
          float cc = cosT[fidx * S_LEN + n], ss = sinT[fidx * S_LEN + n];
          float lo = acc[p][nf][j4], hi = acc[p + 2][nf][j4];
          acc[p][nf][j4]     = lo * cc - hi * ss;
          acc[p + 2][nf][j4] = hi * cc + lo * ss;
        }
      }
  }

  if (MODE == 1 && m0 < 1536) {
    __syncthreads();
    u16t* Cs = smem;
#pragma unroll
    for (int i = 0; i < 4; ++i)
#pragma unroll
      for (int nf = 0; nf < 4; ++nf) {
        int n_l = wc * 64 + nf * 16 + ln15;
        int m_l = wr * 64 + i * 16 + ln4 * 4;
        union { u16t h[4]; uint2 u2; } pk;
#pragma unroll
        for (int j4 = 0; j4 < 4; ++j4) pk.h[j4] = f2bf_u16(acc[i][nf][j4]);
        *(uint2*)(Cs + n_l * 136 + m_l) = pk.u2;
      }
    __syncthreads();
    u16t* Co = (u16t*)C1;   // qkT [4096][1536]
#pragma unroll
    for (int it = 0; it < 8; ++it) {
      int idx = it * 256 + t;
      int row = idx >> 4, ch = idx & 15;
      *(uint4*)&Co[(size_t)(n0 + row) * 1536 + m0 + ch * 8] =
          *(const uint4*)&Cs[row * 136 + ch * 8];
    }
  } else if (MODE == 1) {
    __syncthreads();
    u16t* Cs = smem;
#pragma unroll
    for (int i = 0; i < 4; ++i)
#pragma unroll
      for (int j4 = 0; j4 < 4; ++j4) {
        int mrow = wr * 64 + i * 16 + ln4 * 4 + j4;
#pragma unroll
        for (int nf = 0; nf < 4; ++nf) {
          int col = wc * 64 + nf * 16 + ln15;
          Cs[mrow * 128 + col] = f2bf_u16(acc[i][nf][j4]);
        }
      }
    __syncthreads();
    u16t* Co = (u16t*)C2;
#pragma unroll
    for (int it = 0; it < 8; ++it) {
      int idx = it * 256 + t;
      int row = idx >> 4, ch = idx & 15;
      *(uint4*)&Co[(size_t)(m0 - 1536 + row) * S_LEN + n0 + ch * 8] =
          *(const uint4*)&Cs[row * 128 + ch * 8];
    }
  } else {
    float* Co = (float*)C1;
#pragma unroll
    for (int i = 0; i < 4; ++i)
#pragma unroll
      for (int j4 = 0; j4 < 4; ++j4) {
        int m = m0 + wr * 64 + i * 16 + ln4 * 4 + j4;
#pragma unroll
        for (int nf = 0; nf < 4; ++nf)
          Co[(size_t)m * S_LEN + n0 + wc * 64 + nf * 16 + ln15] = acc[i][nf][j4];
      }
  }
}

// ---------------- windowed attention via MFMA ----------------
// round-13 version (staged K/V via global_load_lds; predicated amask loads).
// LDS staging is REQUIRED here: direct-global fragment reads scatter across
// token rows (3KB lane stride) and quadruple intra-block K traffic (round-14
// regression, +11 us). Staging = coalesce + dedupe, not just a cache.
__global__ __launch_bounds__(256, 3) void attn_kernel(
    const u16t* __restrict__ qkT, const u16t* __restrict__ vbuf,
    const float* __restrict__ amask, u16t* __restrict__ attnT)
{
  __shared__ __align__(16) u16t sm[24576];   // 49152 B
  u16t* KP = sm;           // Kt rows stride 64, later P rows stride 192
  u16t* Vt = sm + 12288;   // rows stride 192

  const int t = threadIdx.x;
  const int lane = t & 63, w = t >> 6;
  const int fr = lane & 15, fc = lane >> 4;

  const int nid = (blockIdx.x & 7) * 96 + (blockIdx.x >> 3);
  const int h = nid / 64, qt = nid % 64;
  const int q0 = qt * 64;
  const int kstart = q0 - 64;

  if (q0 == 0) {
    *(uint4*)(KP + t * 8) = make_uint4(0, 0, 0, 0);
    *(uint4*)(KP + 2048 + t * 8) = make_uint4(0, 0, 0, 0);
#pragma unroll
    for (int j = 0; j < 2; ++j) {
      int unit = t + 256 * j;
      *(uint4*)(Vt + (unit >> 3) * 192 + (unit & 7) * 8) = make_uint4(0, 0, 0, 0);
    }
  } else if (q0 == S_LEN - 64) {
    *(uint4*)(KP + 8192 + t * 8) = make_uint4(0, 0, 0, 0);
    *(uint4*)(KP + 10240 + t * 8) = make_uint4(0, 0, 0, 0);
#pragma unroll
    for (int j = 0; j < 2; ++j) {
      int unit = t + 256 * j;
      *(uint4*)(Vt + (unit >> 3) * 192 + 128 + (unit & 7) * 8) = make_uint4(0, 0, 0, 0);
    }
  }

  const u16t* kcolbase = qkT + 768 + h * 64;
#pragma unroll
  for (int jj = 0; jj < 6; ++jj) {
    int ii = jj * 256 + t;
    int row = ii >> 3, ch = ii & 7;
    int key = kstart + row;
    if (key >= 0 && key < S_LEN)
      stage16(kcolbase + (size_t)key * 1536 + ((ch ^ (row & 7)) * 8),
              KP + (jj * 256 + w * 64) * 8);
  }
#pragma unroll
  for (int jj = 0; jj < 6; ++jj) {
    int ii = jj * 256 + t;
    int row = ii / 24, ch = ii - row * 24;
    int sc = (ch & 24) | ((ch & 7) ^ (row & 7));
    int kf = kstart + sc * 8;
    if (kf >= 0 && kf < S_LEN)
      stage16(vbuf + (size_t)(h * 64 + row) * S_LEN + kf,
              Vt + (jj * 256 + w * 64) * 8);
  }
  const u16t* qrow = qkT + (size_t)(q0 + w * 16 + fr) * 1536 + h * 64;
  bf16x8 qa0 = *(const bf16x8*)(qrow + fc * 8);
  bf16x8 qa1 = *(const bf16x8*)(qrow + 32 + fc * 8);

  // amask: predicated issue-early loads (only in-window lanes fetch)
  float am[12][4];
  const int qb = q0 + w * 16 + fc * 4;
#pragma unroll
  for (int nt = 0; nt < 12; ++nt) {
    int kk = nt * 16 + fr;
    int key = kstart + kk;
#pragma unroll
    for (int r = 0; r < 4; ++r) {
      int q = w * 16 + fc * 4 + r;
      int dk = kk - q;
      bool inw = (key >= 0) && (key < S_LEN) && (dk >= 0) && (dk <= 128);
      am[nt][r] = inw ? amask[(size_t)(qb + r) * S_LEN + key] : 0.f;
    }
  }

  __syncthreads();

  f32x4 acc[12];
#pragma unroll
  for (int nt = 0; nt < 12; ++nt) acc[nt] = (f32x4){0.f, 0.f, 0.f, 0.f};
  __builtin_amdgcn_s_setprio(1);
#pragma unroll
  for (int nt = 0; nt < 12; ++nt) {
    int row = nt * 16 + fr;
    bf16x8 kb0 = *(const bf16x8*)(KP + row * 64 + ((fc ^ (fr & 7)) * 8));
    acc[nt] = __builtin_amdgcn_mfma_f32_16x16x32_bf16(qa0, kb0, acc[nt], 0, 0, 0);
    bf16x8 kb1 = *(const bf16x8*)(KP + row * 64 + (((4 + fc) ^ (fr & 7)) * 8));
    acc[nt] = __builtin_amdgcn_mfma_f32_16x16x32_bf16(qa1, kb1, acc[nt], 0, 0, 0);
  }
  __builtin_amdgcn_s_setprio(0);

  float rm[4] = {-3.0e38f, -3.0e38f, -3.0e38f, -3.0e38f};
#pragma unroll
  for (int nt = 0; nt < 12; ++nt) {
    int kk = nt * 16 + fr;
    int key = kstart + kk;
#pragma unroll
    for (int r = 0; r < 4; ++r) {
      int q = w * 16 + fc * 4 + r;
      int dk = kk - q;
      bool inw = (key >= 0) && (key < S_LEN) && (dk >= 0) && (dk <= 128);
      float s = -3.0e38f;
      if (inw) s = acc[nt][r] * 0.125f + am[nt][r];
      acc[nt][r] = s;
      rm[r] = fmaxf(rm[r], s);
    }
  }
#pragma unroll
  for (int r = 0; r < 4; ++r)
#pragma unroll
    for (int off = 1; off < 16; off <<= 1)
      rm[r] = fmaxf(rm[r], __shfl_xor(rm[r], off));

  float rs[4] = {0.f, 0.f, 0.f, 0.f};
#pragma unroll
  for (int nt = 0; nt < 12; ++nt)
#pragma unroll
    for (int r = 0; r < 4; ++r) {
      float e = __expf(acc[nt][r] - rm[r]);
      acc[nt][r] = e;
      rs[r] += e;
    }
#pragma unroll
  for (int r = 0; r < 4; ++r)
#pragma unroll
    for (int off = 1; off < 16; off <<= 1)
      rs[r] += __shfl_xor(rs[r], off);

  __syncthreads();   // all waves done reading Kt -> safe to overwrite with P

#pragma unroll
  for (int nt = 0; nt < 12; ++nt) {
    int kk = nt * 16 + fr;
    int cg = kk >> 3;
#pragma unroll
    for (int r = 0; r < 4; ++r) {
      int q = w * 16 + fc * 4 + r;
      int csw = (cg & 24) | ((cg & 7) ^ (q & 7));
      KP[q * 192 + csw * 8 + (kk & 7)] = f2bf_u16(acc[nt][r]);
    }
  }
  // no barrier: PV reads only this wave's P rows; within-wave RAW is lgkm-ordered

  f32x4 acc2[4];
#pragma unroll
  for (int nt = 0; nt < 4; ++nt) acc2[nt] = (f32x4){0.f, 0.f, 0.f, 0.f};
  __builtin_amdgcn_s_setprio(1);
#pragma unroll
  for (int c32 = 0; c32 < 6; ++c32) {
    int cg = c32 * 4 + fc;
    int csA = (cg & 24) | ((cg & 7) ^ (fr & 7));
    bf16x8 pa = *(const bf16x8*)(KP + (w * 16 + fr) * 192 + csA * 8);
#pragma unroll
    for (int nt = 0; nt < 4; ++nt) {
      int d = nt * 16 + fr;
      bf16x8 vb = *(const bf16x8*)(Vt + d * 192 + csA * 8);
      acc2[nt] = __builtin_amdgcn_mfma_f32_16x16x32_bf16(pa, vb, acc2[nt], 0, 0, 0);
    }
  }
  __builtin_amdgcn_s_setprio(0);

  float inv[4];
#pragma unroll
  for (int r = 0; r < 4; ++r) inv[r] = 1.f / rs[r];
#pragma unroll
  for (int nt = 0; nt < 4; ++nt)
#pragma unroll
    for (int r = 0; r < 4; ++r) {
      int q = w * 16 + fc * 4 + r;
      int d = nt * 16 + fr;
      attnT[(size_t)(q0 + q) * 768 + h * 64 + d] = f2bf_u16(acc2[nt][r] * inv[r]);
    }
}

extern "C" void kernel_launch(void* const* d_in, const int* in_sizes, int n_in,
                              void* d_out, int out_size, void* d_ws, size_t ws_size,
                              hipStream_t stream) {
  const float* x     = (const float*)d_in[0];
  const int*   pos   = (const int*)d_in[1];
  const float* amask = (const float*)d_in[2];
  const float* qkvw  = (const float*)d_in[3];
  const float* outw  = (const float*)d_in[4];
  float* out = (float*)d_out;

  char* ws = (char*)d_ws;
  float* cosT   = (float*)ws;                          ws += 32 * S_LEN * 4;
  float* sinT   = (float*)ws;                          ws += 32 * S_LEN * 4;
  u16t*  xT     = (u16t*)ws;                           ws += (size_t)S_LEN * 768 * 2;
  u16t*  wq_bf  = (u16t*)ws;                           ws += (size_t)2304 * 768 * 2;
  u16t*  wo_bf  = (u16t*)ws;                           ws += (size_t)768 * 768 * 2;
  u16t*  qkT    = (u16t*)ws;                           ws += (size_t)S_LEN * 1536 * 2;
  u16t*  vbuf   = (u16t*)ws;                           ws += (size_t)768 * S_LEN * 2;
  u16t*  attnT  = (u16t*)ws;

  // fused prep: tcast(768) | castw wq(1728) | castw wo(576) | rope(512)
  prep_kernel<<<3584, 256, 0, stream>>>(x, xT, qkvw, wq_bf, outw, wo_bf, pos, cosT, sinT);
  // QKV: 18x32 tiles, XCD rect = 9m x 8n
  gemm_kernel<1><<<576, 256, 0, stream>>>(wq_bf, xT, qkT, vbuf, cosT, sinT, 1536, 32, 8, 9);
  attn_kernel<<<768, 256, 0, stream>>>(qkT, vbuf, amask, attnT);
  // out-proj: 6x32 tiles, XCD rect = 6m x 4n
  gemm_kernel<0><<<192, 256, 0, stream>>>(wo_bf, attnT, out, nullptr, cosT, sinT, 0, 32, 4, 6);
}